// Round 8
// baseline (313.680 us; speedup 1.0000x reference)
//
#include <hip/hip_runtime.h>
#include <cstddef>

#define A_ATOMS 96
#define BATCH   128
#define NNODES  12288   // B*A
#define NB      8       // nodes per block (node_k)
#define AS      132     // AsL / workS stride (132%32=4)
#define XS      196     // xinS stride (196%32=4)

typedef float v2f __attribute__((ext_vector_type(2)));

__device__ __forceinline__ float silu_f(float x) {
    float e = __expf(-x);
    return x * __builtin_amdgcn_rcpf(1.0f + e);
}
__device__ __forceinline__ v2f silu2(v2f x) {
    v2f r; r.x = silu_f(x.x); r.y = silu_f(x.y); return r;
}

#define RED64(v) { v += __shfl_xor(v, 1); v += __shfl_xor(v, 2); v += __shfl_xor(v, 4); \
                   v += __shfl_xor(v, 8); v += __shfl_xor(v, 16); v += __shfl_xor(v, 32); }
#define RED8(v)  { v += __shfl_xor(v, 1); v += __shfl_xor(v, 2); v += __shfl_xor(v, 4); }

// ===== node kernel v4: 128 threads, 8 cols/thread, vW in regs, 4 barriers ===
// tx = t&15 (cols tx*8..+7), ty = t>>4 (node ty, vrep rows 3ty..3ty+2).
__global__ __launch_bounds__(128)
void node_k(const float* __restrict__ vrep, const float* __restrict__ mixW1,
            const float* __restrict__ srep,
            const float* __restrict__ sc1W1, const float* __restrict__ sc1b1,
            const float* __restrict__ sc1W2, const float* __restrict__ sc1b2,
            const float* __restrict__ mixW2,
            const float* __restrict__ sc2W1, const float* __restrict__ sc2b1,
            const float* __restrict__ sc2W2, const float* __restrict__ sc2b2,
            float* __restrict__ l0v, float* __restrict__ l1v) {
    __shared__ float AsL[24 * AS];      // vrep tile; later aliased as hmid
    __shared__ float xinS[NB * XS];     // xin; later x1 s-half
    __shared__ float s1s[2][64];
    __shared__ float vn2s[NB];
    __shared__ float pw2s[NB][3];

    const int t  = threadIdx.x;
    const int tx = t & 15;
    const int ty = t >> 4;
    const int row0  = blockIdx.x * 24;
    const int node0 = blockIdx.x * NB;

    // ---------- stage 0: vrep tile (24x128) + srep (8x128) into LDS ---------
#pragma unroll
    for (int it = 0; it < 6; it++) {
        const int idx = it * 128 + t;           // 768 float4
        const int r   = idx >> 5;
        const int c4  = (idx & 31) * 4;
        *(float4*)&AsL[r * AS + c4] = *(const float4*)(vrep + (size_t)(row0 + r) * 128 + c4);
    }
#pragma unroll
    for (int it = 0; it < 2; it++) {            // 256 float4
        const int idx = it * 128 + t;
        const int a   = idx >> 5;
        const int c4  = (idx & 31) * 4;
        *(float4*)&xinS[a * XS + c4] = *(const float4*)(srep + (size_t)(node0 + a) * 128 + c4);
    }
    __syncthreads();

    // ---------- stage 1: vmix rows 3ty..+2, cols tx*8..+7 -------------------
    float acc[3][8];
#pragma unroll
    for (int i = 0; i < 3; i++)
#pragma unroll
        for (int j = 0; j < 8; j++) acc[i][j] = 0.0f;

    for (int kc = 0; kc < 128; kc += 8) {
        float a0[8], a1[8], a2[8];
        *(float4*)&a0[0] = *(const float4*)&AsL[(3 * ty + 0) * AS + kc];
        *(float4*)&a0[4] = *(const float4*)&AsL[(3 * ty + 0) * AS + kc + 4];
        *(float4*)&a1[0] = *(const float4*)&AsL[(3 * ty + 1) * AS + kc];
        *(float4*)&a1[4] = *(const float4*)&AsL[(3 * ty + 1) * AS + kc + 4];
        *(float4*)&a2[0] = *(const float4*)&AsL[(3 * ty + 2) * AS + kc];
        *(float4*)&a2[4] = *(const float4*)&AsL[(3 * ty + 2) * AS + kc + 4];
#pragma unroll
        for (int kk = 0; kk < 8; kk++) {
            float b[8];
            *(float4*)&b[0] = *(const float4*)(mixW1 + (size_t)(kc + kk) * 128 + tx * 8);
            *(float4*)&b[4] = *(const float4*)(mixW1 + (size_t)(kc + kk) * 128 + tx * 8 + 4);
#pragma unroll
            for (int j = 0; j < 8; j++) {
                acc[0][j] += a0[kk] * b[j];
                acc[1][j] += a1[kk] * b[j];
                acc[2][j] += a2[kk] * b[j];
            }
        }
    }
    // tx<8: V half (cols 0..63) -> norms into xin cols 128..191.
    // tx>=8: W half (cols 64..127) stays live in acc[][] until stage 5a.
    if (tx < 8) {
        float nrm[8];
#pragma unroll
        for (int c = 0; c < 8; c++)
            nrm[c] = sqrtf(acc[0][c] * acc[0][c] + acc[1][c] * acc[1][c]
                         + acc[2][c] * acc[2][c]);
        *(float4*)&xinS[ty * XS + 128 + tx * 8]     = *(float4*)&nrm[0];
        *(float4*)&xinS[ty * XS + 128 + tx * 8 + 4] = *(float4*)&nrm[4];
    }
    __syncthreads();

    // ---------- stage 3: hmid = silu(xin @ sc1W1 + b1), K=192 ---------------
    float* workS = AsL;                 // AsL reads all done (pre-barrier)
    {
        float acc3[8];
#pragma unroll
        for (int j = 0; j < 8; j++) acc3[j] = 0.0f;
        for (int kc = 0; kc < 192; kc += 8) {
            float af[8];
            *(float4*)&af[0] = *(const float4*)&xinS[ty * XS + kc];
            *(float4*)&af[4] = *(const float4*)&xinS[ty * XS + kc + 4];
#pragma unroll
            for (int kk = 0; kk < 8; kk++) {
                float b[8];
                *(float4*)&b[0] = *(const float4*)(sc1W1 + (size_t)(kc + kk) * 128 + tx * 8);
                *(float4*)&b[4] = *(const float4*)(sc1W1 + (size_t)(kc + kk) * 128 + tx * 8 + 4);
#pragma unroll
                for (int j = 0; j < 8; j++) acc3[j] += af[kk] * b[j];
            }
        }
        float h[8];
#pragma unroll
        for (int j = 0; j < 8; j++) h[j] = silu_f(acc3[j] + sc1b1[tx * 8 + j]);
        *(float4*)&workS[ty * AS + tx * 8]     = *(float4*)&h[0];
        *(float4*)&workS[ty * AS + tx * 8 + 4] = *(float4*)&h[4];
    }
    __syncthreads();

    // ---------- stage 4: x1 = hmid @ sc1W2 + b2, K=128 ----------------------
    float xg[8];                        // gate cols (tx>=8) stay in regs
    {
        float acc4[8];
#pragma unroll
        for (int j = 0; j < 8; j++) acc4[j] = 0.0f;
        for (int kc = 0; kc < 128; kc += 8) {
            float af[8];
            *(float4*)&af[0] = *(const float4*)&workS[ty * AS + kc];
            *(float4*)&af[4] = *(const float4*)&workS[ty * AS + kc + 4];
#pragma unroll
            for (int kk = 0; kk < 8; kk++) {
                float b[8];
                *(float4*)&b[0] = *(const float4*)(sc1W2 + (size_t)(kc + kk) * 128 + tx * 8);
                *(float4*)&b[4] = *(const float4*)(sc1W2 + (size_t)(kc + kk) * 128 + tx * 8 + 4);
#pragma unroll
                for (int j = 0; j < 8; j++) acc4[j] += af[kk] * b[j];
            }
        }
        if (tx < 8) {                   // s-half -> LDS (silu applied in 5b)
            float xs[8];
#pragma unroll
            for (int j = 0; j < 8; j++) xs[j] = acc4[j] + sc1b2[tx * 8 + j];
            *(float4*)&xinS[ty * XS + tx * 8]     = *(float4*)&xs[0];
            *(float4*)&xinS[ty * XS + tx * 8 + 4] = *(float4*)&xs[4];
        } else {
#pragma unroll
            for (int j = 0; j < 8; j++) xg[j] = acc4[j] + sc1b2[tx * 8 + j];
        }
    }

    // ---------- stage 5a: vW*gate . mixW2, 8-lane reduction (tx 8..15) ------
    if (tx >= 8) {
        float p0 = 0, p1 = 0, p2 = 0, p3 = 0, p4 = 0, p5 = 0;
#pragma unroll
        for (int c = 0; c < 8; c++) {
            float2 m = *(const float2*)(mixW2 + (size_t)((tx - 8) * 8 + c) * 2);
            const float v0 = xg[c] * acc[0][c];
            const float v1 = xg[c] * acc[1][c];
            const float v2 = xg[c] * acc[2][c];
            p0 += v0 * m.x; p1 += v0 * m.y;
            p2 += v1 * m.x; p3 += v1 * m.y;
            p4 += v2 * m.x; p5 += v2 * m.y;
        }
        RED8(p0); RED8(p1); RED8(p2); RED8(p3); RED8(p4); RED8(p5);
        if (tx == 8) {
            vn2s[ty] = sqrtf(p0 * p0 + p2 * p2 + p4 * p4);
            pw2s[ty][0] = p1; pw2s[ty][1] = p3; pw2s[ty][2] = p5;
        }
    }
    __syncthreads();

    // ---------- stage 5b: block-2 MLP (64-wide) per node --------------------
    {
        const int w = t >> 6, lane = t & 63;
        const float bb1 = sc2b1[lane];
        const float wn  = sc2W1[64 * 64 + lane];
        const float wq0 = sc2W2[lane * 2 + 0], wq1 = sc2W2[lane * 2 + 1];
#pragma unroll
        for (int r = 0; r < 4; r++) {
            const int nl = r * 2 + w;
            const float s1 = silu_f(xinS[nl * XS + lane]);
            s1s[w][lane] = s1;
            __builtin_amdgcn_s_waitcnt(0);   // lgkmcnt(0): own-wave LDS visible
            float acc5 = bb1 + vn2s[nl] * wn;
#pragma unroll 8
            for (int i2 = 0; i2 < 64; i2++) acc5 += s1s[w][i2] * sc2W1[i2 * 64 + lane];
            const float h2 = silu_f(acc5);
            float q0 = h2 * wq0, q1 = h2 * wq1;
            RED64(q0); RED64(q1);
            if (lane == 0) {
                const int n = node0 + nl;
                const float gate = q1 + sc2b2[1];
                l0v[n] = q0 + sc2b2[0];
                l1v[(size_t)n * 3 + 0] = gate * pw2s[nl][0];
                l1v[(size_t)n * 3 + 1] = gate * pw2s[nl][1];
                l1v[(size_t)n * 3 + 2] = gate * pw2s[nl][2];
            }
        }
    }
}

// ---------- pairpre v3: interleaved PT table [h][j][8] ----------------------
// PT[(h*NN+j)*8 + {0..2}] = Pv_a, {3..5} = Pr_a, {6} = Ps, {7} = pad
__global__ __launch_bounds__(256)
void pairpre_k(const float* __restrict__ l1v, const float* __restrict__ pos,
               const float* __restrict__ l0v,
               const float* __restrict__ vvW1, const float* __restrict__ vrW1,
               const float* __restrict__ sW1, const float* __restrict__ sb1,
               float* __restrict__ PT) {
    const int jl = threadIdx.x & 31;
    const int hq = threadIdx.x >> 5;        // 0..7
    const int j  = blockIdx.x * 32 + jl;
    const float lj0 = l1v[j * 3 + 0], lj1 = l1v[j * 3 + 1], lj2 = l1v[j * 3 + 2];
    const float pj0 = pos[j * 3 + 0], pj1 = pos[j * 3 + 1], pj2 = pos[j * 3 + 2];
    const float l0j = l0v[j];
#pragma unroll
    for (int hh = 0; hh < 4; hh++) {
        const int h = hq * 4 + hh;
        if (h < 30) {
            float pv[3], pr[3];
#pragma unroll
            for (int a = 0; a < 3; a++) {
                pv[a] = lj0 * vvW1[(3 * a + 0) * 30 + h] + lj1 * vvW1[(3 * a + 1) * 30 + h]
                      + lj2 * vvW1[(3 * a + 2) * 30 + h];
                pr[a] = pj0 * vrW1[(3 * a + 0) * 30 + h] + pj1 * vrW1[(3 * a + 1) * 30 + h]
                      + pj2 * vrW1[(3 * a + 2) * 30 + h];
            }
            const float ps = sb1[h] + l0j * sW1[30 + h];
            float4 q0 = { pv[0], pv[1], pv[2], pr[0] };
            float4 q1 = { pr[1], pr[2], ps, 0.0f };
            float* p = PT + ((size_t)h * NNODES + j) * 8;
            *(float4*)p       = q0;
            *(float4*)(p + 4) = q1;
        }
    }
}

#define PKFMA(a, b, c) __builtin_elementwise_fma((a), (b), (c))

// ---------- pair kernel v4: 2 i-atoms/thread, PT loads, forced pk-fma -------
__global__ __launch_bounds__(192)
void pair_k(const float* __restrict__ l0v, const float* __restrict__ l1v,
            const float* __restrict__ PT,
            const float* __restrict__ vvb1, const float* __restrict__ vrb1,
            const float* __restrict__ sW1,
            const float* __restrict__ vvW2, const float* __restrict__ vrW2,
            const float* __restrict__ sW2,
            const float* __restrict__ vvb2, const float* __restrict__ vrb2,
            const float* __restrict__ sb2,
            const float* __restrict__ hW1,  const float* __restrict__ hb1,
            const float* __restrict__ hW2,  const float* __restrict__ hb2,
            float* __restrict__ out) {
    const int t = threadIdx.x;
    const int b = blockIdx.y;
    const int g = (t >= 96) ? 1 : 0;
    const int j = t - g * 96;
    const int i0 = blockIdx.x * 4 + g * 2;
    const int ni0 = b * A_ATOMS + i0;
    const int ni1 = ni0 + 1;
    const int nj  = b * A_ATOMS + j;

    const v2f li0 = { l1v[ni0 * 3 + 0], l1v[ni1 * 3 + 0] };
    const v2f li1 = { l1v[ni0 * 3 + 1], l1v[ni1 * 3 + 1] };
    const v2f li2 = { l1v[ni0 * 3 + 2], l1v[ni1 * 3 + 2] };
    const v2f s0i = { l0v[ni0], l0v[ni1] };

    v2f t9[9];
#pragma unroll
    for (int l = 0; l < 9; l++) t9[l] = (v2f)(vvb2[l] + vrb2[l] + sb2[l]);

    const float* pt = PT + (size_t)nj * 8;
    for (int h = 0; h < 30; h++) {
        float4 q0 = *(const float4*)(pt + (size_t)h * NNODES * 8);
        float4 q1 = *(const float4*)(pt + (size_t)h * NNODES * 8 + 4);

        v2f av = PKFMA(li2, (v2f)(q0.z), PKFMA(li1, (v2f)(q0.y),
                 PKFMA(li0, (v2f)(q0.x), (v2f)(vvb1[h]))));
        v2f ar = PKFMA(li2, (v2f)(q1.y), PKFMA(li1, (v2f)(q1.x),
                 PKFMA(li0, (v2f)(q0.w), (v2f)(vrb1[h]))));
        v2f as = PKFMA(s0i, (v2f)(sW1[h]), (v2f)(q1.z));
        av = silu2(av); ar = silu2(ar); as = silu2(as);
#pragma unroll
        for (int l = 0; l < 9; l++) {
            t9[l] = PKFMA(av, (v2f)(vvW2[h * 9 + l]), t9[l]);
            t9[l] = PKFMA(ar, (v2f)(vrW2[h * 9 + l]), t9[l]);
            t9[l] = PKFMA(as, (v2f)(sW2[h * 9 + l]), t9[l]);
        }
    }

    v2f o9[9];
#pragma unroll
    for (int l = 0; l < 9; l++) o9[l] = (v2f)(hb2[l]);
    for (int h = 0; h < 30; h++) {
        v2f a = (v2f)(hb1[h]);
#pragma unroll
        for (int m = 0; m < 9; m++) a = PKFMA(t9[m], (v2f)(hW1[m * 30 + h]), a);
        a = silu2(a);
#pragma unroll
        for (int l = 0; l < 9; l++) o9[l] = PKFMA(a, (v2f)(hW2[h * 9 + l]), o9[l]);
    }

    // out[((b*A+i)*3+k)*288 + j*3 + l]
    const size_t rb0 = (size_t)ni0;
#pragma unroll
    for (int k = 0; k < 3; k++) {
        const size_t off0 = (rb0 * 3 + k) * 288 + (size_t)j * 3;
        const size_t off1 = off0 + 3 * 288;
        out[off0 + 0] = o9[3 * k + 0].x;
        out[off0 + 1] = o9[3 * k + 1].x;
        out[off0 + 2] = o9[3 * k + 2].x;
        out[off1 + 0] = o9[3 * k + 0].y;
        out[off1 + 1] = o9[3 * k + 1].y;
        out[off1 + 2] = o9[3 * k + 2].y;
    }
}

extern "C" void kernel_launch(void* const* d_in, const int* in_sizes, int n_in,
                              void* d_out, int out_size, void* d_ws, size_t ws_size,
                              hipStream_t stream) {
    const float* pos   = (const float*)d_in[0];
    const float* srep  = (const float*)d_in[1];
    const float* vrep  = (const float*)d_in[2];
    const float* mixW1 = (const float*)d_in[3];
    const float* sc1W1 = (const float*)d_in[4];
    const float* sc1b1 = (const float*)d_in[5];
    const float* sc1W2 = (const float*)d_in[6];
    const float* sc1b2 = (const float*)d_in[7];
    const float* mixW2 = (const float*)d_in[8];
    const float* sc2W1 = (const float*)d_in[9];
    const float* sc2b1 = (const float*)d_in[10];
    const float* sc2W2 = (const float*)d_in[11];
    const float* sc2b2 = (const float*)d_in[12];
    const float* vvW1  = (const float*)d_in[13];
    const float* vvb1  = (const float*)d_in[14];
    const float* vvW2  = (const float*)d_in[15];
    const float* vvb2  = (const float*)d_in[16];
    const float* vrW1  = (const float*)d_in[17];
    const float* vrb1  = (const float*)d_in[18];
    const float* vrW2  = (const float*)d_in[19];
    const float* vrb2  = (const float*)d_in[20];
    const float* sW1   = (const float*)d_in[21];
    const float* sb1   = (const float*)d_in[22];
    const float* sW2   = (const float*)d_in[23];
    const float* sb2   = (const float*)d_in[24];
    const float* hW1   = (const float*)d_in[25];
    const float* hb1   = (const float*)d_in[26];
    const float* hW2   = (const float*)d_in[27];
    const float* hb2   = (const float*)d_in[28];

    float* ws  = (float*)d_ws;
    float* PT  = ws;                    // 30*12288*8 = 2,949,120
    float* l0v = PT + 2949120;          // 12,288
    float* l1v = l0v + 12288;           // 36,864
    float* outf = (float*)d_out;

    // 1. fused node stage -> l0, l1
    node_k<<<NNODES / NB, 128, 0, stream>>>(
        vrep, mixW1, srep,
        sc1W1, sc1b1, sc1W2, sc1b2,
        mixW2, sc2W1, sc2b1, sc2W2, sc2b2,
        l0v, l1v);

    // 2. interleaved P-table
    pairpre_k<<<NNODES / 32, 256, 0, stream>>>(l1v, pos, l0v, vvW1, vrW1,
                                               sW1, sb1, PT);

    // 3. pair stage (2 i per thread, packed f32, PT loads)
    pair_k<<<dim3(A_ATOMS / 4, BATCH), 192, 0, stream>>>(
        l0v, l1v, PT,
        vvb1, vrb1, sW1,
        vvW2, vrW2, sW2,
        vvb2, vrb2, sb2,
        hW1, hb1, hW2, hb2,
        outf);
}